// Round 7
// baseline (123.256 us; speedup 1.0000x reference)
//
#include <hip/hip_runtime.h>

#define BB 128
#define NN 1152
#define KD 512
#define NC 10
#define ND 16
#define CD 160   // NC*ND

typedef unsigned short ushort_t;
typedef unsigned int uint_t;
typedef short short8v __attribute__((ext_vector_type(8)));
typedef float float4v __attribute__((ext_vector_type(4)));

__device__ __forceinline__ float bf2f(ushort_t u) {
  return __uint_as_float(((uint_t)u) << 16);
}
__device__ __forceinline__ ushort_t f2bf(float f) {
  uint_t x = __float_as_uint(f);
  x += 0x7fffu + ((x >> 16) & 1u);   // round-to-nearest-even
  return (ushort_t)(x >> 16);
}

// Barrier that does NOT drain vmcnt: LDS-visibility (lgkmcnt) only.
#define BAR_LDS() do {                                   \
    __builtin_amdgcn_sched_barrier(0);                   \
    asm volatile("s_waitcnt lgkmcnt(0)" ::: "memory");   \
    __builtin_amdgcn_s_barrier();                        \
    __builtin_amdgcn_sched_barrier(0);                   \
  } while (0)

// ---------- W transpose+convert: Wt[n][k] = bf16(W[k][n]), [160][512] ----------
__global__ __launch_bounds__(256) void wconv(const float* __restrict__ W,
                                             ushort_t* __restrict__ Wt) {
  int idx = blockIdx.x * 256 + threadIdx.x;   // 81920 total
  int n = idx >> 9, k = idx & 511;
  Wt[idx] = f2bf(W[(size_t)k * CD + n]);
}

// ---------- GEMM via MFMA: BK=32, A+B LDS double-buffered, 28KB LDS ----------
// BM=64, BK=32, 256 thr = 4 waves; wave w = rows w*16..+16, all 160 cols.
// 16 k-steps; ONE lgkmcnt-only barrier per step; vmcnt never drained.
// LDS rows are 64B (4 x 16B slots); swizzle slot ^= (row>>1)&3 -> exactly
// 2-way bank aliasing (free) on both write and ds_read_b128.
// Layout: A[0]=0..4K, A[1]=4..8K, B[0]=8..18.25K, B[1]=18.25..28.5K.
// Epilogue: Ct union @0 (21KB), sA @24576 (2.5KB). Total 28672 B -> 5 blk/CU.
__global__ __launch_bounds__(256, 4) void gemm_mfma(
    const float* __restrict__ x, const ushort_t* __restrict__ Wt,
    ushort_t* __restrict__ uhat, float* __restrict__ partials) {
  __shared__ __align__(16) char smem[28672];
  const int tid = threadIdx.x;
  const int wave = tid >> 6, lane = tid & 63;
  const int lrow = lane & 15, lg = lane >> 4;
  const int row0 = blockIdx.x * 64;

  float4v acc[10];
#pragma unroll
  for (int nt = 0; nt < 10; ++nt)
#pragma unroll
    for (int r = 0; r < 4; ++r) acc[nt][r] = 0.f;

  // A staging: thread -> row arow_=tid>>2 (0..63), slot as=tid&3 (8 floats->16B)
  const int arow_ = tid >> 2;
  const int as = tid & 3;
  const int aby = (arow_ << 6) + ((as ^ ((arow_ >> 1) & 3)) << 4);
  // B staging: pieces f=tid+i*256 (f<640): row=f>>2 (0..159), slot=f&3
  int bsrc[3], bby[3];
#pragma unroll
  for (int i = 0; i < 3; ++i) {
    int f = tid + i * 256;
    int br = f >> 2, bs = f & 3;
    bsrc[i] = br * KD + bs * 8;
    bby[i] = (br << 6) + ((bs ^ ((br >> 1) & 3)) << 4);
  }
  const bool b2ok = (tid + 512) < 640;

  float4v rA[2];
  short8v rB[3];

  auto LOADS = [&](int ks) {
    int k0 = ks * 32;
    const float* p = x + (size_t)(row0 + arow_) * KD + k0 + as * 8;
    rA[0] = *reinterpret_cast<const float4v*>(p);
    rA[1] = *reinterpret_cast<const float4v*>(p + 4);
    rB[0] = *reinterpret_cast<const short8v*>(Wt + bsrc[0] + k0);
    rB[1] = *reinterpret_cast<const short8v*>(Wt + bsrc[1] + k0);
    if (b2ok) rB[2] = *reinterpret_cast<const short8v*>(Wt + bsrc[2] + k0);
  };
  auto WRITES = [&](int buf) {
    char* Ab = smem + buf * 4096;
    char* Bb = smem + 8192 + buf * 10240;
    short8v pk;
#pragma unroll
    for (int e = 0; e < 4; ++e) {
      pk[e] = (short)f2bf(rA[0][e]);
      pk[e + 4] = (short)f2bf(rA[1][e]);
    }
    *reinterpret_cast<short8v*>(Ab + aby) = pk;
    *reinterpret_cast<short8v*>(Bb + bby[0]) = rB[0];
    *reinterpret_cast<short8v*>(Bb + bby[1]) = rB[1];
    if (b2ok) *reinterpret_cast<short8v*>(Bb + bby[2]) = rB[2];
  };

  const int arow = wave * 16 + lrow;
  const int afrag_by = (arow << 6) + ((lg ^ ((arow >> 1) & 3)) << 4);
  LOADS(0);
  WRITES(0);
  LOADS(1);
  BAR_LDS();                             // tile 0 visible
  int cur = 0;
  for (int ks = 0; ks < 16; ++ks) {
    const char* Ab = smem + cur * 4096;
    const char* Bb = smem + 8192 + cur * 10240;
    short8v a = *reinterpret_cast<const short8v*>(Ab + afrag_by);
#pragma unroll
    for (int nt = 0; nt < 10; ++nt) {
      int brow = nt * 16 + lrow;
      int bbyte = (brow << 6) + ((lg ^ ((brow >> 1) & 3)) << 4);
      short8v bfr = *reinterpret_cast<const short8v*>(Bb + bbyte);
      acc[nt] = __builtin_amdgcn_mfma_f32_16x16x32_bf16(a, bfr, acc[nt], 0, 0, 0);
    }
    if (ks < 15) {
      WRITES(cur ^ 1);                   // tile ks+1 -> other buf
      if (ks < 14) LOADS(ks + 2);
    }
    BAR_LDS();
    cur ^= 1;
  }

  // ---- passA partials: col-sums over this block's 64 rows
  float* sAf = reinterpret_cast<float*>(smem + 24576);   // [4][160]
#pragma unroll
  for (int nt = 0; nt < 10; ++nt) {
    float p = acc[nt][0] + acc[nt][1] + acc[nt][2] + acc[nt][3];
    p += __shfl_xor(p, 16);
    p += __shfl_xor(p, 32);
    if (lg == 0) sAf[wave * CD + nt * 16 + lrow] = p;
  }

  // ---- C repack through LDS union -> coalesced 16B stores
  ushort_t* Ct = reinterpret_cast<ushort_t*>(smem);     // [64][168] = 21504 B
#pragma unroll
  for (int nt = 0; nt < 10; ++nt)
#pragma unroll
    for (int r = 0; r < 4; ++r) {
      int row = wave * 16 + lg * 4 + r;
      Ct[row * 168 + nt * 16 + lrow] = f2bf(acc[nt][r]);
    }
  __syncthreads();
  if (tid < CD) {
    float s = sAf[tid] + sAf[CD + tid] + sAf[2 * CD + tid] + sAf[3 * CD + tid];
    partials[(size_t)blockIdx.x * CD + tid] = s;
  }
#pragma unroll
  for (int i = 0; i < 5; ++i) {
    int p = tid + i * 256;
    int row = p / 20, c0 = (p % 20) * 8;
    *reinterpret_cast<short8v*>(&uhat[(size_t)(row0 + row) * CD + c0]) =
        *reinterpret_cast<const short8v*>(&Ct[row * 168 + c0]);
  }
}

// ---------- routing iteration with fused v-computation ----------
#define ITER_T 640
template <int ITER2>
__global__ __launch_bounds__(ITER_T) void iter_k(
    const ushort_t* __restrict__ uhat, const float* __restrict__ pg,
    const float* __restrict__ p1, float* __restrict__ pout) {
  __shared__ float bv[128][NC];        // 5120 B
  __shared__ float wv[128][NC];        // 5120 B
  __shared__ float sred[32][CD];       // 20480 B
  __shared__ float sred2[4][CD];       // 2560 B
  __shared__ float vv[CD];             // 640 B
  const int blk = blockIdx.x;
  const int b = blk / 9, ch = blk % 9;
  const int t = threadIdx.x;
  const int g = t / 20, q = t % 20;
  const int c = q >> 1;
  const ushort_t* ub = uhat + ((size_t)b * NN + ch * 128) * CD + q * 8;

  // ---- prologue: compute vv (= v0, or v0+v1 for ITER2)
  if (t < CD) {
    float s0 = 0.f;
#pragma unroll
    for (int cc = 0; cc < 18; ++cc) s0 += pg[((size_t)b * 18 + cc) * CD + t];
    s0 *= 0.1f;
    float ss = s0 * s0;
    ss += __shfl_xor(ss, 1); ss += __shfl_xor(ss, 2);
    ss += __shfl_xor(ss, 4); ss += __shfl_xor(ss, 8);
    float sn = sqrtf(ss) + 1e-7f;
    float v = s0 * sn / (1.f + sn * sn);
    if (ITER2) {
      float s1 = 0.f;
#pragma unroll
      for (int cc = 0; cc < 9; ++cc) s1 += p1[((size_t)b * 9 + cc) * CD + t];
      float ss1 = s1 * s1;
      ss1 += __shfl_xor(ss1, 1); ss1 += __shfl_xor(ss1, 2);
      ss1 += __shfl_xor(ss1, 4); ss1 += __shfl_xor(ss1, 8);
      float sn1 = sqrtf(ss1) + 1e-7f;
      v += s1 * sn1 / (1.f + sn1 * sn1);
    }
    vv[t] = v;
  }
  __syncthreads();

  float v0r[8];
  {
    float4v a = *reinterpret_cast<const float4v*>(&vv[q * 8]);
    float4v bb = *reinterpret_cast<const float4v*>(&vv[q * 8 + 4]);
#pragma unroll
    for (int e = 0; e < 4; ++e) { v0r[e] = a[e]; v0r[e + 4] = bb[e]; }
  }

  // ---- phase 1: logits
  short8v u8[4];
#pragma unroll
  for (int it = 0; it < 4; ++it) {
    int n = g + it * 32;
    u8[it] = *reinterpret_cast<const short8v*>(ub + (size_t)n * CD);
    float p = 0.f;
#pragma unroll
    for (int e = 0; e < 8; ++e) p += bf2f((ushort_t)u8[it][e]) * v0r[e];
    p += __shfl_xor(p, 1);
    if ((q & 1) == 0) bv[n][c] = p;
  }
  __syncthreads();

  // ---- phase 1.5: softmax weights once per row
  if (t < 128) {
    float e[NC];
    float bm = bv[t][0];
#pragma unroll
    for (int cc = 1; cc < NC; ++cc) bm = fmaxf(bm, bv[t][cc]);
    float Z = 0.f;
#pragma unroll
    for (int cc = 0; cc < NC; ++cc) { e[cc] = __expf(bv[t][cc] - bm); Z += e[cc]; }
    float rz = 1.f / Z;
#pragma unroll
    for (int cc = 0; cc < NC; ++cc) wv[t][cc] = e[cc] * rz;
  }
  __syncthreads();

  // ---- phase 2: weighted accumulate
  float a[8];
#pragma unroll
  for (int e = 0; e < 8; ++e) a[e] = 0.f;
#pragma unroll
  for (int it = 0; it < 4; ++it) {
    int n = g + it * 32;
    float w = wv[n][c];
#pragma unroll
    for (int e = 0; e < 8; ++e) a[e] += w * bf2f((ushort_t)u8[it][e]);
  }
  {
    float4v lo, hi;
#pragma unroll
    for (int e = 0; e < 4; ++e) { lo[e] = a[e]; hi[e] = a[e + 4]; }
    float4v* dst = reinterpret_cast<float4v*>(&sred[g][q * 8]);
    dst[0] = lo; dst[1] = hi;
  }
  __syncthreads();
  {
    int col = t % CD, part = t / CD;    // 640 = 4 x 160
    float s = 0.f;
#pragma unroll
    for (int g8 = 0; g8 < 8; ++g8) s += sred[part * 8 + g8][col];
    sred2[part][col] = s;
  }
  __syncthreads();
  if (t < CD) {
    pout[(size_t)blk * CD + t] =
        sred2[0][t] + sred2[1][t] + sred2[2][t] + sred2[3][t];
  }
}

// ---------- final squash ----------
__global__ __launch_bounds__(CD) void squash_out(
    const float* __restrict__ p2, float* __restrict__ outp) {
  int b = blockIdx.x, t = threadIdx.x;
  float s = 0.f;
#pragma unroll
  for (int cc = 0; cc < 9; ++cc) s += p2[((size_t)b * 9 + cc) * CD + t];
  float ss = s * s;
  ss += __shfl_xor(ss, 1); ss += __shfl_xor(ss, 2);
  ss += __shfl_xor(ss, 4); ss += __shfl_xor(ss, 8);
  float sn = sqrtf(ss) + 1e-7f;
  outp[(size_t)b * CD + t] = s * sn / (1.f + sn * sn);
}

extern "C" void kernel_launch(void* const* d_in, const int* in_sizes, int n_in,
                              void* d_out, int out_size, void* d_ws, size_t ws_size,
                              hipStream_t stream) {
  const float* x = (const float*)d_in[0];   // [128,1152,512] f32
  const float* W = (const float*)d_in[1];   // [512,160] f32
  float* out = (float*)d_out;               // [128,10,16] f32

  char* ws = (char*)d_ws;
  ushort_t* uhat = (ushort_t*)ws;                          // 47,185,920 B
  ushort_t* Wt   = (ushort_t*)(ws + 47185920);             //    163,840 B
  float*    pg   = (float*)(ws + 47185920 + 163840);       //  1,474,560 B  [2304][160]
  float*    p1   = (float*)(ws + 48824320);                //    737,280 B  [1152][160]
  float*    p2   = (float*)(ws + 49561600);                //    737,280 B  [1152][160]

  wconv<<<320, 256, 0, stream>>>(W, Wt);
  gemm_mfma<<<2304, 256, 0, stream>>>(x, Wt, uhat, pg);
  iter_k<0><<<1152, ITER_T, 0, stream>>>(uhat, pg, nullptr, p1);  // s1 partials
  iter_k<1><<<1152, ITER_T, 0, stream>>>(uhat, pg, p1, p2);       // s2 partials
  squash_out<<<BB, CD, 0, stream>>>(p2, out);                     // out = v2
}